// Round 1
// baseline (8493.555 us; speedup 1.0000x reference)
//
#include <hip/hip_runtime.h>
#include <cstdint>
#include <cstddef>

// ============================================================================
// LSTM forecaster, MI355X.
//   Phase A (setup0/setup1): fold encoder into weights (Wfuse = Wih@enc_W,
//     b2 = bih+bhh+Wih@enc_b), convert weights/x to bf16, zero h slot0 + bars.
//   Phase B (lstm_persist): ONE persistent kernel runs all 704 sequential
//     steps. 8 independent barrier groups (16 batches each) x 32 feature
//     blocks. Weights live in VGPRs as MFMA B-fragments for the whole run;
//     cell state c lives in one register per thread.
//   Phase C (final_proj): [89984,512]x[512,64] bf16 MFMA GEMM -> d_out fp32.
// ============================================================================

typedef __bf16 bf16x8 __attribute__((ext_vector_type(8)));
typedef float  f32x4  __attribute__((ext_vector_type(4)));

// ---- workspace layout (bytes) ----
static constexpr size_t SZ_HALL = (size_t)705 * 128 * 512 * 2;  // h slots 0..704
static constexpr size_t SZ_WCAT = (size_t)2048 * 576 * 2;       // [Whh | Wfuse] bf16
static constexpr size_t SZ_WIH  = (size_t)2048 * 512 * 2;       // Wih bf16 (AR phase)
static constexpr size_t SZ_DECW = (size_t)64 * 512 * 2;         // dec_W bf16
static constexpr size_t SZ_XT   = (size_t)512 * 128 * 64 * 2;   // x transposed [t][b][c] bf16
static constexpr size_t OFF_HALL = 0;
static constexpr size_t OFF_WCAT = OFF_HALL + SZ_HALL;
static constexpr size_t OFF_WIH  = OFF_WCAT + SZ_WCAT;
static constexpr size_t OFF_DECW = OFF_WIH + SZ_WIH;
static constexpr size_t OFF_XT   = OFF_DECW + SZ_DECW;
static constexpr size_t OFF_B2   = OFF_XT + SZ_XT;              // 2048 f32
static constexpr size_t OFF_BAR_ = OFF_B2 + 2048 * 4;
static constexpr size_t OFF_BAT  = OFF_BAR_ + 2048 * 4;         // barrier area 4KB
static constexpr size_t WS_NEEDED = OFF_BAT + 4096;

// ---------------------------------------------------------------------------
// setup0: grid-stride conversions / zeroing. All ws state rebuilt every call
// (ws is re-poisoned to 0xAA before each timed launch).
// ---------------------------------------------------------------------------
__global__ void __launch_bounds__(256)
setup0(const float* __restrict__ x, const float* __restrict__ Wih,
       const float* __restrict__ Whh, const float* __restrict__ bih,
       const float* __restrict__ bhh, const float* __restrict__ decW,
       __bf16* __restrict__ xT, __bf16* __restrict__ Wih_bf,
       __bf16* __restrict__ Wcat, __bf16* __restrict__ decW_bf,
       float* __restrict__ b_ar, __bf16* __restrict__ h0,
       unsigned* __restrict__ bar)
{
  size_t gid = (size_t)blockIdx.x * blockDim.x + threadIdx.x;
  size_t gsz = (size_t)gridDim.x * blockDim.x;
  // xT[t][b][c] = bf16(x[b][t][c])
  for (size_t i = gid; i < 4194304u; i += gsz) {
    size_t t = i >> 13, b = (i >> 6) & 127u, c = i & 63u;
    xT[i] = (__bf16)x[(b * 512 + t) * 64 + c];
  }
  for (size_t i = gid; i < 1048576u; i += gsz) Wih_bf[i] = (__bf16)Wih[i];
  for (size_t i = gid; i < 1048576u; i += gsz) {
    size_t r = i >> 9, k = i & 511u;
    Wcat[r * 576 + k] = (__bf16)Whh[i];          // cols 0..511 = Whh
  }
  for (size_t i = gid; i < 32768u; i += gsz) decW_bf[i] = (__bf16)decW[i];
  for (size_t i = gid; i < 2048u; i += gsz) b_ar[i] = bih[i] + bhh[i];
  for (size_t i = gid; i < 65536u; i += gsz) h0[i] = (__bf16)0.f;  // h slot 0 = 0
  for (size_t i = gid; i < 1024u; i += gsz) bar[i] = 0u;           // barriers = 0
}

// ---------------------------------------------------------------------------
// setup1: Wfuse = Wih @ enc_W  ->  Wcat cols 512..575 ; b2 = bih+bhh+Wih@enc_b
// One wave per output row r.
// ---------------------------------------------------------------------------
__global__ void __launch_bounds__(64)
setup1(const float* __restrict__ Wih, const float* __restrict__ encW,
       const float* __restrict__ encb, const float* __restrict__ bih,
       const float* __restrict__ bhh, __bf16* __restrict__ Wcat,
       float* __restrict__ b2)
{
  int r = blockIdx.x;        // 0..2047
  int c = threadIdx.x;       // 0..63
  const float* wr = Wih + (size_t)r * 512;
  float acc = 0.f;
  for (int k = 0; k < 512; ++k) acc += wr[k] * encW[(size_t)k * 64 + c];
  Wcat[(size_t)r * 576 + 512 + c] = (__bf16)acc;
  float p = 0.f;
  for (int kk = 0; kk < 8; ++kk) { int k = kk * 64 + c; p += wr[k] * encb[k]; }
  for (int off = 32; off > 0; off >>= 1) p += __shfl_down(p, off);
  if (c == 0) b2[r] = bih[r] + bhh[r] + p;
}

// ---------------------------------------------------------------------------
// Persistent recurrent kernel.
// block = 256 threads (4 waves, one per gate i/f/g/o).
// bid = g*32 + fb : group g (batches g*16..+16), feature block fb (f0=fb*16).
// Step t (1..704): pre = [h_{t-1} | x_{t-1}] @ Wcat_slice.T   (K=576 main,
//                  pre = h_{t-1} @ Wih_slice.T                 K=512 AR)
// MFMA 16x16x32 bf16: A lane&15 = batch row, k = quad*8+j ; B lane&15 = gate
// row; D col=lane&15 (gate feat), row=quad*4+reg (batch).
// ---------------------------------------------------------------------------
template<bool MAIN>
__device__ __forceinline__ void lstm_step(
    unsigned t, int tid, int wv, int n16, int quad, int b0, int f0,
    int em, int ef, const bf16x8 (&wf)[18],
    __bf16* __restrict__ h_all, const __bf16* __restrict__ xT,
    const float* __restrict__ bias, float& creg,
    __bf16 (*A)[584], float (*ex)[16][17],
    unsigned* cnt, unsigned* gen)
{
  // ---- group barrier wait: all 32 blocks of this group finished step t-1 ----
  if (t > 1) {
    if (tid == 0) {
      while (__hip_atomic_load(gen, __ATOMIC_RELAXED, __HIP_MEMORY_SCOPE_AGENT) < t - 1u)
        __builtin_amdgcn_s_sleep(1);
      __threadfence();   // acquire: drop stale L1/L2 before reading h_{t-1}
    }
  }
  __syncthreads();

  // ---- stage A = [h rows | x row-chunk] into LDS ----
  const __bf16* hsrc = h_all + (size_t)(t - 1) * 65536 + (size_t)b0 * 512;
  #pragma unroll
  for (int it = 0; it < 4; ++it) {
    int lin = it * 256 + tid;                 // 0..1023: 16 rows x 64 chunks
    int row = lin >> 6, ch = lin & 63;
    *(uint4*)(&A[row][ch * 8]) = *(const uint4*)(hsrc + (size_t)row * 512 + ch * 8);
  }
  if (MAIN && tid < 128) {                    // x_t: 16 rows x 64 bf16 at cols 512..575
    int row = tid >> 3, ch = tid & 7;
    *(uint4*)(&A[row][512 + ch * 8]) =
        *(const uint4*)(xT + (size_t)(t - 1) * 8192 + (size_t)(b0 + row) * 64 + ch * 8);
  }
  __syncthreads();

  // ---- MFMA: this wave's gate, 16 features, K=576/512 (AR skips f-gate) ----
  if (MAIN || wv != 1) {
    f32x4 a0 = {0.f, 0.f, 0.f, 0.f}, a1 = {0.f, 0.f, 0.f, 0.f};
    const __bf16* arow = &A[n16][quad * 8];
    #pragma unroll
    for (int kc = 0; kc < (MAIN ? 18 : 16); ++kc) {
      bf16x8 af = *(const bf16x8*)(arow + kc * 32);
      if (kc & 1) a1 = __builtin_amdgcn_mfma_f32_16x16x32_bf16(af, wf[kc], a1, 0, 0, 0);
      else        a0 = __builtin_amdgcn_mfma_f32_16x16x32_bf16(af, wf[kc], a0, 0, 0, 0);
    }
    a0 += a1;
    #pragma unroll
    for (int r = 0; r < 4; ++r) ex[wv][n16][quad * 4 + r] = a0[r];  // [gate][feat][batch]
  }
  __syncthreads();

  // ---- gates / state update: thread (em=batch row, ef=feature) ----
  {
    float pi = ex[0][ef][em] + bias[f0 + ef];
    float pf = ex[1][ef][em] + bias[512 + f0 + ef];
    float pg = ex[2][ef][em] + bias[1024 + f0 + ef];
    float po = ex[3][ef][em] + bias[1536 + f0 + ef];
    float ig = 1.f / (1.f + __expf(-pi));
    float gg = tanhf(pg);
    float og = 1.f / (1.f + __expf(-po));
    float c2;
    if (MAIN) { float fg = 1.f / (1.f + __expf(-pf)); c2 = fg * creg + ig * gg; creg = c2; }
    else      { c2 = ig * gg; (void)pf; }      // AR: zero state -> c2 = i*g
    float h2 = og * tanhf(c2);
    h_all[(size_t)t * 65536 + (size_t)(b0 + em) * 512 + f0 + ef] = (__bf16)h2;
  }
  __syncthreads();   // drains vmcnt: all h stores complete before arrival

  // ---- group barrier arrive ----
  if (tid == 0) {
    __threadfence();  // release: flush XCD L2 so other XCDs' blocks see h_t
    unsigned old = __hip_atomic_fetch_add(cnt, 1u, __ATOMIC_RELAXED, __HIP_MEMORY_SCOPE_AGENT);
    if ((old & 31u) == 31u)
      __hip_atomic_store(gen, t, __ATOMIC_RELAXED, __HIP_MEMORY_SCOPE_AGENT);
  }
}

__global__ void __launch_bounds__(256)
lstm_persist(const __bf16* __restrict__ xT, const __bf16* __restrict__ Wcat,
             const __bf16* __restrict__ Wih_bf, const float* __restrict__ b2,
             const float* __restrict__ b_ar, __bf16* __restrict__ h_all,
             unsigned* __restrict__ bar)
{
  const int bid = blockIdx.x;
  const int g = bid >> 5, fb = bid & 31;
  const int b0 = g * 16, f0 = fb * 16;
  const int tid = threadIdx.x;
  const int wv = tid >> 6, lane = tid & 63;
  const int n16 = lane & 15, quad = lane >> 4;
  const int em = tid >> 4, ef = tid & 15;

  __shared__ __align__(16) __bf16 A[16][584];   // 16 batch rows x (512 h + 64 x + pad)
  __shared__ float ex[4][16][17];               // gate exchange, padded stride

  unsigned* cnt = bar + g * 64;                 // 256B per group; cnt/gen 128B apart
  unsigned* gen = bar + g * 64 + 32;

  // persistent weight fragments: wf[kc] = W[gate row = wv*512+f0+n16][kc*32+quad*8 ..+8]
  bf16x8 wf[18];
  {
    const __bf16* wrow = Wcat + (size_t)(wv * 512 + f0 + n16) * 576 + quad * 8;
    #pragma unroll
    for (int kc = 0; kc < 18; ++kc) wf[kc] = *(const bf16x8*)(wrow + kc * 32);
  }
  float creg = 0.f;   // cell state c[b0+em][f0+ef], fp32, lives here all 512 steps

  for (unsigned t = 1; t <= 512; ++t)
    lstm_step<true>(t, tid, wv, n16, quad, b0, f0, em, ef, wf,
                    h_all, xT, b2, creg, A, ex, cnt, gen);

  { // AR phase feeds h into Wih (zero recurrent state): swap weight slice
    const __bf16* wrow = Wih_bf + (size_t)(wv * 512 + f0 + n16) * 512 + quad * 8;
    #pragma unroll
    for (int kc = 0; kc < 16; ++kc) wf[kc] = *(const bf16x8*)(wrow + kc * 32);
  }
  for (unsigned t = 513; t <= 704; ++t)
    lstm_step<false>(t, tid, wv, n16, quad, b0, f0, em, ef, wf,
                     h_all, xT, b_ar, creg, A, ex, cnt, gen);
}

// ---------------------------------------------------------------------------
// final_proj: out[b][j][c] = h_slot[j+2][b][:] @ dec_W.T + dec_b, j=0..702.
// h_all viewed as [90240, 512]; rows 256..90239 are a contiguous GEMM A.
// block = 128 rows x 64 cols; wave w: rows +w*32 (2 m-tiles), all 4 n-tiles.
// ---------------------------------------------------------------------------
__global__ void __launch_bounds__(256)
final_proj(const __bf16* __restrict__ h_all, const __bf16* __restrict__ decW_bf,
           const float* __restrict__ decb, float* __restrict__ out)
{
  const int bi = blockIdx.x;               // 0..702
  const int tid = threadIdx.x;
  const int wv = tid >> 6, lane = tid & 63;
  const int n16 = lane & 15, quad = lane >> 4;
  const size_t r0 = 256 + (size_t)bi * 128 + (size_t)wv * 32;

  f32x4 acc[2][4];
  #pragma unroll
  for (int mt = 0; mt < 2; ++mt)
    #pragma unroll
    for (int nt = 0; nt < 4; ++nt) acc[mt][nt] = f32x4{0.f, 0.f, 0.f, 0.f};

  const __bf16* arow0 = h_all + (r0 + n16) * 512 + quad * 8;
  const __bf16* arow1 = arow0 + 16 * 512;
  const __bf16* brow  = decW_bf + (size_t)n16 * 512 + quad * 8;

  #pragma unroll
  for (int kc = 0; kc < 16; ++kc) {
    bf16x8 a0 = *(const bf16x8*)(arow0 + kc * 32);
    bf16x8 a1 = *(const bf16x8*)(arow1 + kc * 32);
    #pragma unroll
    for (int nt = 0; nt < 4; ++nt) {
      bf16x8 b = *(const bf16x8*)(brow + (size_t)nt * 8192 + kc * 32);
      acc[0][nt] = __builtin_amdgcn_mfma_f32_16x16x32_bf16(a0, b, acc[0][nt], 0, 0, 0);
      acc[1][nt] = __builtin_amdgcn_mfma_f32_16x16x32_bf16(a1, b, acc[1][nt], 0, 0, 0);
    }
  }
  #pragma unroll
  for (int mt = 0; mt < 2; ++mt)
    #pragma unroll
    for (int nt = 0; nt < 4; ++nt)
      #pragma unroll
      for (int r = 0; r < 4; ++r) {
        size_t R = r0 + mt * 16 + quad * 4 + r;      // h_all row
        int slot = (int)(R >> 7), b = (int)(R & 127);
        int j = slot - 2;
        int c = nt * 16 + n16;
        out[((size_t)b * 703 + j) * 64 + c] = acc[mt][nt][r] + decb[c];
      }
}

// ---------------------------------------------------------------------------
extern "C" void kernel_launch(void* const* d_in, const int* in_sizes, int n_in,
                              void* d_out, int out_size, void* d_ws, size_t ws_size,
                              hipStream_t stream)
{
  const float* x    = (const float*)d_in[0];
  const float* encW = (const float*)d_in[1];
  const float* encb = (const float*)d_in[2];
  const float* Wih  = (const float*)d_in[3];
  const float* Whh  = (const float*)d_in[4];
  const float* bih  = (const float*)d_in[5];
  const float* bhh  = (const float*)d_in[6];
  const float* decW = (const float*)d_in[7];
  const float* decb = (const float*)d_in[8];
  float* out = (float*)d_out;

  if (ws_size < WS_NEEDED) return;  // need ~100.5 MiB of scratch

  char* ws = (char*)d_ws;
  __bf16*   h_all   = (__bf16*)(ws + OFF_HALL);
  __bf16*   Wcat    = (__bf16*)(ws + OFF_WCAT);
  __bf16*   Wih_bf  = (__bf16*)(ws + OFF_WIH);
  __bf16*   decW_bf = (__bf16*)(ws + OFF_DECW);
  __bf16*   xT      = (__bf16*)(ws + OFF_XT);
  float*    b2      = (float*)(ws + OFF_B2);
  float*    b_ar    = (float*)(ws + OFF_BAR_);
  unsigned* bar     = (unsigned*)(ws + OFF_BAT);

  hipLaunchKernelGGL(setup0, dim3(2048), dim3(256), 0, stream,
                     x, Wih, Whh, bih, bhh, decW, xT, Wih_bf, Wcat, decW_bf,
                     b_ar, h_all, bar);
  hipLaunchKernelGGL(setup1, dim3(2048), dim3(64), 0, stream,
                     Wih, encW, encb, bih, bhh, Wcat, b2);
  hipLaunchKernelGGL(lstm_persist, dim3(256), dim3(256), 0, stream,
                     xT, Wcat, Wih_bf, b2, b_ar, h_all, bar);
  hipLaunchKernelGGL(final_proj, dim3(703), dim3(256), 0, stream,
                     h_all, decW_bf, decb, out);
}

// Round 2
// 2773.304 us; speedup vs baseline: 3.0626x; 3.0626x over previous
//
#include <hip/hip_runtime.h>
#include <cstdint>
#include <cstddef>

// ============================================================================
// LSTM forecaster, MI355X — R2: fence-free data-flow pipeline.
//   Sync between the 32 feature-blocks of a batch-group is done purely by
//   polling the h data itself: h slots are pre-filled with bf16 NaN sentinel
//   (h = o*tanh(c) can never be NaN), producers publish h via 8B agent-scope
//   atomic stores (straight to LLC), consumers poll with 8B agent-scope
//   atomic loads. No __threadfence, no barriers, no atomic RMW.
// ============================================================================

typedef __bf16 bf16x8 __attribute__((ext_vector_type(8)));
typedef float  f32x4  __attribute__((ext_vector_type(4)));

static constexpr unsigned long long SENT = 0x7FC07FC07FC07FC0ULL;  // 4x bf16 NaN

// ---- workspace layout (bytes) ----
static constexpr size_t SZ_HALL = (size_t)705 * 128 * 512 * 2;  // h slots 0..704
static constexpr size_t SZ_WCAT = (size_t)2048 * 576 * 2;       // [Whh | Wfuse] bf16
static constexpr size_t SZ_WIH  = (size_t)2048 * 512 * 2;       // Wih bf16 (AR phase)
static constexpr size_t SZ_DECW = (size_t)64 * 512 * 2;         // dec_W bf16
static constexpr size_t SZ_XT   = (size_t)512 * 128 * 64 * 2;   // x transposed [t][b][c]
static constexpr size_t OFF_HALL = 0;
static constexpr size_t OFF_WCAT = OFF_HALL + SZ_HALL;
static constexpr size_t OFF_WIH  = OFF_WCAT + SZ_WCAT;
static constexpr size_t OFF_DECW = OFF_WIH + SZ_WIH;
static constexpr size_t OFF_XT   = OFF_DECW + SZ_DECW;
static constexpr size_t OFF_B2   = OFF_XT + SZ_XT;              // 2048 f32
static constexpr size_t OFF_BAR_ = OFF_B2 + 2048 * 4;           // b_ar 2048 f32
static constexpr size_t WS_NEEDED = OFF_BAR_ + 2048 * 4;

__device__ __forceinline__ float sigm(float x) { return 1.f / (1.f + __expf(-x)); }
__device__ __forceinline__ float tanh_fast(float x) {
  // tanh(x) = 1 - 2/(e^{2x}+1); exp overflow -> +1, underflow -> -1 (correct limits)
  return 1.f - 2.f / (__expf(2.f * x) + 1.f);
}

// ---------------------------------------------------------------------------
// setup0: conversions + h slot0 zeros + h slots 1..704 NaN sentinel fill.
// Rebuilt every call (ws is re-poisoned to 0xAA before each timed launch;
// NOTE 0xAAAA is a legit bf16 value, so the NaN fill is mandatory).
// ---------------------------------------------------------------------------
__global__ void __launch_bounds__(256)
setup0(const float* __restrict__ x, const float* __restrict__ Wih,
       const float* __restrict__ Whh, const float* __restrict__ bih,
       const float* __restrict__ bhh, const float* __restrict__ decW,
       __bf16* __restrict__ xT, __bf16* __restrict__ Wih_bf,
       __bf16* __restrict__ Wcat, __bf16* __restrict__ decW_bf,
       float* __restrict__ b_ar, __bf16* __restrict__ h_all)
{
  size_t gid = (size_t)blockIdx.x * blockDim.x + threadIdx.x;
  size_t gsz = (size_t)gridDim.x * blockDim.x;
  // xT[t][b][c] = bf16(x[b][t][c])
  for (size_t i = gid; i < 4194304u; i += gsz) {
    size_t t = i >> 13, b = (i >> 6) & 127u, c = i & 63u;
    xT[i] = (__bf16)x[(b * 512 + t) * 64 + c];
  }
  for (size_t i = gid; i < 1048576u; i += gsz) Wih_bf[i] = (__bf16)Wih[i];
  for (size_t i = gid; i < 1048576u; i += gsz) {
    size_t r = i >> 9, k = i & 511u;
    Wcat[r * 576 + k] = (__bf16)Whh[i];          // cols 0..511 = Whh
  }
  for (size_t i = gid; i < 32768u; i += gsz) decW_bf[i] = (__bf16)decW[i];
  for (size_t i = gid; i < 2048u; i += gsz) b_ar[i] = bih[i] + bhh[i];
  unsigned long long* hp = (unsigned long long*)h_all;
  for (size_t i = gid; i < 16384u; i += gsz) hp[i] = 0ULL;               // slot 0 = 0
  for (size_t i = 16384u + gid; i < 11550720u; i += gsz) hp[i] = SENT;   // slots 1..704
}

// ---------------------------------------------------------------------------
// setup1: Wfuse = Wih @ enc_W  ->  Wcat cols 512..575 ; b2 = bih+bhh+Wih@enc_b
// ---------------------------------------------------------------------------
__global__ void __launch_bounds__(64)
setup1(const float* __restrict__ Wih, const float* __restrict__ encW,
       const float* __restrict__ encb, const float* __restrict__ bih,
       const float* __restrict__ bhh, __bf16* __restrict__ Wcat,
       float* __restrict__ b2)
{
  int r = blockIdx.x;        // 0..2047
  int c = threadIdx.x;       // 0..63
  const float* wr = Wih + (size_t)r * 512;
  float acc = 0.f;
  for (int k = 0; k < 512; ++k) acc += wr[k] * encW[(size_t)k * 64 + c];
  Wcat[(size_t)r * 576 + 512 + c] = (__bf16)acc;
  float p = 0.f;
  for (int kk = 0; kk < 8; ++kk) { int k = kk * 64 + c; p += wr[k] * encb[k]; }
  for (int off = 32; off > 0; off >>= 1) p += __shfl_down(p, off);
  if (c == 0) b2[r] = bih[r] + bhh[r] + p;
}

// ---------------------------------------------------------------------------
// One LSTM step, data-flow synchronized.
// block = 256 thr (4 waves, one gate each). bid = g*32+fb.
// ---------------------------------------------------------------------------
template<bool MAIN>
__device__ __forceinline__ void lstm_step(
    unsigned t, int tid, int wv, int lane, int b0, int f0,
    const bf16x8 (&wf)[18], float bv,
    __bf16* __restrict__ h_all, const __bf16* __restrict__ xT,
    f32x4& creg, __bf16 (*A)[584], float (*ex)[16][17])
{
  const int n16 = lane & 15, quad = lane >> 4;

  // ---- x prefetch (normal cached load; L2-resident) ----
  uint4 xv;
  if (MAIN && tid < 128)
    xv = *(const uint4*)(xT + (size_t)(t - 1) * 8192 +
                         (size_t)(b0 + (tid >> 3)) * 64 + (tid & 7) * 8);

  // ---- poll h_{t-1}: 8 x 8B pieces per thread, selective re-load ----
  const unsigned long long* src = (const unsigned long long*)
      (h_all + (size_t)(t - 1) * 65536 + (size_t)(b0 + (tid >> 4)) * 512) +
      (size_t)(tid & 15) * 8;
  unsigned long long v[8];
  unsigned bad = 0xFFu;
  do {
    unsigned nb = 0;
    #pragma unroll
    for (int i = 0; i < 8; ++i)
      if (bad & (1u << i))
        v[i] = __hip_atomic_load(src + i, __ATOMIC_RELAXED, __HIP_MEMORY_SCOPE_AGENT);
    #pragma unroll
    for (int i = 0; i < 8; ++i)
      if ((bad & (1u << i)) && v[i] == SENT) nb |= 1u << i;
    bad = nb;
  } while (bad);

  // ---- stage A (data already in registers from the poll) ----
  {
    unsigned long long* ad = (unsigned long long*)&A[tid >> 4][(tid & 15) * 32];
    #pragma unroll
    for (int i = 0; i < 8; ++i) ad[i] = v[i];
  }
  if (MAIN && tid < 128)
    *(uint4*)(&A[tid >> 3][512 + (tid & 7) * 8]) = xv;
  __syncthreads();

  // ---- MFMA: wave wv = gate wv; bias pre-loaded into accumulator ----
  if (MAIN || wv != 1) {
    f32x4 a0 = {bv, bv, bv, bv}, a1 = {0.f, 0.f, 0.f, 0.f};
    const __bf16* arow = &A[n16][quad * 8];
    #pragma unroll
    for (int kc = 0; kc < (MAIN ? 18 : 16); ++kc) {
      bf16x8 af = *(const bf16x8*)(arow + kc * 32);
      if (kc & 1) a1 = __builtin_amdgcn_mfma_f32_16x16x32_bf16(af, wf[kc], a1, 0, 0, 0);
      else        a0 = __builtin_amdgcn_mfma_f32_16x16x32_bf16(af, wf[kc], a0, 0, 0, 0);
    }
    a0 += a1;
    #pragma unroll
    for (int r = 0; r < 4; ++r) ex[wv][n16][quad * 4 + r] = a0[r];  // [gate][feat][batch]
  }
  __syncthreads();

  // ---- gates: 16 lanes per wave each produce one 8B piece (4 feats x 1 batch) ----
  if (lane < 16) {
    const int em = wv * 4 + (lane >> 2), p = lane & 3;
    unsigned long long pk = 0;
    #pragma unroll
    for (int j = 0; j < 4; ++j) {
      const int ef = p * 4 + j;
      float ig = sigm(ex[0][ef][em]);
      float gg = tanh_fast(ex[2][ef][em]);
      float og = sigm(ex[3][ef][em]);
      float c2;
      if (MAIN) { float fg = sigm(ex[1][ef][em]); c2 = fg * creg[j] + ig * gg; creg[j] = c2; }
      else      { c2 = ig * gg; }               // AR: zero state
      float h2 = og * tanh_fast(c2);
      __bf16 hb = (__bf16)h2;
      pk |= (unsigned long long)__builtin_bit_cast(unsigned short, hb) << (16 * j);
    }
    unsigned long long* dst = (unsigned long long*)
        (h_all + (size_t)t * 65536 + (size_t)(b0 + em) * 512 + f0) + p;
    __hip_atomic_store(dst, pk, __ATOMIC_RELAXED, __HIP_MEMORY_SCOPE_AGENT);
  }
  // no trailing barrier: next step's LDS writes are ordered by the two
  // __syncthreads above; h publication is the atomic store itself.
}

__global__ void __launch_bounds__(256)
lstm_persist(const __bf16* __restrict__ xT, const __bf16* __restrict__ Wcat,
             const __bf16* __restrict__ Wih_bf, const float* __restrict__ b2,
             const float* __restrict__ b_ar, __bf16* __restrict__ h_all)
{
  const int bid = blockIdx.x;
  const int g = bid >> 5, fb = bid & 31;
  const int b0 = g * 16, f0 = fb * 16;
  const int tid = threadIdx.x;
  const int wv = tid >> 6, lane = tid & 63;
  const int n16 = lane & 15, quad = lane >> 4;

  __shared__ __align__(16) __bf16 A[16][584];   // 16 batch rows x (512 h + 64 x + pad)
  __shared__ float ex[4][16][17];               // gate exchange

  // persistent weight fragments (VGPR-resident all 704 steps)
  bf16x8 wf[18];
  {
    const __bf16* wrow = Wcat + (size_t)(wv * 512 + f0 + n16) * 576 + quad * 8;
    #pragma unroll
    for (int kc = 0; kc < 18; ++kc) wf[kc] = *(const bf16x8*)(wrow + kc * 32);
  }
  float bvm = b2[wv * 512 + f0 + n16];

  f32x4 creg = {0.f, 0.f, 0.f, 0.f};   // cell state (lanes 0..15 of each wave)

  for (unsigned t = 1; t <= 512; ++t)
    lstm_step<true>(t, tid, wv, lane, b0, f0, wf, bvm, h_all, xT, creg, A, ex);

  { // AR phase: h feeds Wih with zero recurrent state
    const __bf16* wrow = Wih_bf + (size_t)(wv * 512 + f0 + n16) * 512 + quad * 8;
    #pragma unroll
    for (int kc = 0; kc < 16; ++kc) wf[kc] = *(const bf16x8*)(wrow + kc * 32);
  }
  float bva = b_ar[wv * 512 + f0 + n16];
  for (unsigned t = 513; t <= 704; ++t)
    lstm_step<false>(t, tid, wv, lane, b0, f0, wf, bva, h_all, xT, creg, A, ex);
}

// ---------------------------------------------------------------------------
// final_proj: out[b][j][c] = h_slot[j+2][b][:] @ dec_W.T + dec_b, j=0..702.
// ---------------------------------------------------------------------------
__global__ void __launch_bounds__(256)
final_proj(const __bf16* __restrict__ h_all, const __bf16* __restrict__ decW_bf,
           const float* __restrict__ decb, float* __restrict__ out)
{
  const int bi = blockIdx.x;               // 0..702
  const int tid = threadIdx.x;
  const int wv = tid >> 6, lane = tid & 63;
  const int n16 = lane & 15, quad = lane >> 4;
  const size_t r0 = 256 + (size_t)bi * 128 + (size_t)wv * 32;

  f32x4 acc[2][4];
  #pragma unroll
  for (int mt = 0; mt < 2; ++mt)
    #pragma unroll
    for (int nt = 0; nt < 4; ++nt) acc[mt][nt] = f32x4{0.f, 0.f, 0.f, 0.f};

  const __bf16* arow0 = h_all + (r0 + n16) * 512 + quad * 8;
  const __bf16* arow1 = arow0 + 16 * 512;
  const __bf16* brow  = decW_bf + (size_t)n16 * 512 + quad * 8;

  #pragma unroll
  for (int kc = 0; kc < 16; ++kc) {
    bf16x8 a0 = *(const bf16x8*)(arow0 + kc * 32);
    bf16x8 a1 = *(const bf16x8*)(arow1 + kc * 32);
    #pragma unroll
    for (int nt = 0; nt < 4; ++nt) {
      bf16x8 b = *(const bf16x8*)(brow + (size_t)nt * 8192 + kc * 32);
      acc[0][nt] = __builtin_amdgcn_mfma_f32_16x16x32_bf16(a0, b, acc[0][nt], 0, 0, 0);
      acc[1][nt] = __builtin_amdgcn_mfma_f32_16x16x32_bf16(a1, b, acc[1][nt], 0, 0, 0);
    }
  }
  #pragma unroll
  for (int mt = 0; mt < 2; ++mt)
    #pragma unroll
    for (int nt = 0; nt < 4; ++nt)
      #pragma unroll
      for (int r = 0; r < 4; ++r) {
        size_t R = r0 + mt * 16 + quad * 4 + r;      // h_all row
        int slot = (int)(R >> 7), b = (int)(R & 127);
        int j = slot - 2;
        int c = nt * 16 + n16;
        out[((size_t)b * 703 + j) * 64 + c] = acc[mt][nt][r] + decb[c];
      }
}

// ---------------------------------------------------------------------------
extern "C" void kernel_launch(void* const* d_in, const int* in_sizes, int n_in,
                              void* d_out, int out_size, void* d_ws, size_t ws_size,
                              hipStream_t stream)
{
  const float* x    = (const float*)d_in[0];
  const float* encW = (const float*)d_in[1];
  const float* encb = (const float*)d_in[2];
  const float* Wih  = (const float*)d_in[3];
  const float* Whh  = (const float*)d_in[4];
  const float* bih  = (const float*)d_in[5];
  const float* bhh  = (const float*)d_in[6];
  const float* decW = (const float*)d_in[7];
  const float* decb = (const float*)d_in[8];
  float* out = (float*)d_out;

  if (ws_size < WS_NEEDED) return;

  char* ws = (char*)d_ws;
  __bf16* h_all   = (__bf16*)(ws + OFF_HALL);
  __bf16* Wcat    = (__bf16*)(ws + OFF_WCAT);
  __bf16* Wih_bf  = (__bf16*)(ws + OFF_WIH);
  __bf16* decW_bf = (__bf16*)(ws + OFF_DECW);
  __bf16* xT      = (__bf16*)(ws + OFF_XT);
  float*  b2      = (float*)(ws + OFF_B2);
  float*  b_ar    = (float*)(ws + OFF_BAR_);

  hipLaunchKernelGGL(setup0, dim3(2048), dim3(256), 0, stream,
                     x, Wih, Whh, bih, bhh, decW, xT, Wih_bf, Wcat, decW_bf,
                     b_ar, h_all);
  hipLaunchKernelGGL(setup1, dim3(2048), dim3(64), 0, stream,
                     Wih, encW, encb, bih, bhh, Wcat, b2);
  hipLaunchKernelGGL(lstm_persist, dim3(256), dim3(256), 0, stream,
                     xT, Wcat, Wih_bf, b2, b_ar, h_all);
  hipLaunchKernelGGL(final_proj, dim3(703), dim3(256), 0, stream,
                     h_all, decW_bf, decb, out);
}